// Round 1
// baseline (886.252 us; speedup 1.0000x reference)
//
#include <hip/hip_runtime.h>
#include <hip/hip_bf16.h>
#include <hip/hip_fp16.h>

// MusicGNN — 3-layer GCN encoder + MLP link predictor.
// N=100000, F_IN=128, HID=64, OUT=32, E=3.2M edges, EL=1M label edges.
// Inputs: float32 (x, weights, biases), int32 (edge indices).
// Output float32: [link_pred (1M) | z (100000*32)] concatenated flat.
//
// R12: replace the two-level bucket sort (bhist/bscan/binA/binB) with a
// direct per-node counting sort: deg-hist (3.2M global atomics over 100k
// counters, ~32 per counter vs 782 serialized RMWs per bucket counter in
// binA), a 3-kernel scan over N, and one scatter pass with returning
// atomics. binA was latency-bound with idle pipes (VALU 1.7%) — the cost
// was atomic contention + serial LDS-atomic chains, not bandwidth. This
// removes one full read+scattered-write round trip of the edge list
// (the `pairs` intermediate) and two kernels.

// ---------------- degree histogram ----------------

__global__ __launch_bounds__(256) void deg_hist(const int* __restrict__ colv,
                                                int* __restrict__ deg, int E) {
    int i = (blockIdx.x * 256 + threadIdx.x) * 4;
    if (i + 4 <= E) {
        int4 c4 = *(const int4*)&colv[i];
        atomicAdd(&deg[c4.x], 1);
        atomicAdd(&deg[c4.y], 1);
        atomicAdd(&deg[c4.z], 1);
        atomicAdd(&deg[c4.w], 1);
    } else {
        for (; i < E; ++i) atomicAdd(&deg[colv[i]], 1);
    }
}

// ---------------- scan: deg -> offsets, cur, dinv ----------------

// scan1: per-block (1024 nodes) sum -> partial[blockIdx]
__global__ __launch_bounds__(256) void scan1(const int* __restrict__ deg,
                                             int* __restrict__ partial, int N) {
    __shared__ int sh[256];
    int base = blockIdx.x * 1024 + threadIdx.x * 4;
    int s = 0;
    if (base + 4 <= N) {
        int4 d = *(const int4*)&deg[base];
        s = d.x + d.y + d.z + d.w;
    } else {
        for (int i = base; i < N; ++i) s += deg[i];
    }
    sh[threadIdx.x] = s;
    __syncthreads();
    for (int off = 128; off > 0; off >>= 1) {
        if (threadIdx.x < off) sh[threadIdx.x] += sh[threadIdx.x + off];
        __syncthreads();
    }
    if (threadIdx.x == 0) partial[blockIdx.x] = sh[0];
}

// scan2: single block, exclusive scan of partial[nb] in place
__global__ __launch_bounds__(128) void scan2(int* __restrict__ partial, int nb) {
    __shared__ int sh[128];
    int v = (threadIdx.x < nb) ? partial[threadIdx.x] : 0;
    sh[threadIdx.x] = v;
    __syncthreads();
#pragma unroll
    for (int off = 1; off < 128; off <<= 1) {
        int y = (threadIdx.x >= (unsigned)off) ? sh[threadIdx.x - off] : 0;
        __syncthreads();
        sh[threadIdx.x] += y;
        __syncthreads();
    }
    if (threadIdx.x < nb) partial[threadIdx.x] = sh[threadIdx.x] - v;  // exclusive
}

// scan3: per-block local exclusive scan + partial base -> offsets, cur, dinv
__global__ __launch_bounds__(256) void scan3(const int* __restrict__ deg,
                                             const int* __restrict__ partial,
                                             int* __restrict__ offsets,
                                             int* __restrict__ cur,
                                             float* __restrict__ dinv, int N, int E) {
    __shared__ int sh[256];
    int base = blockIdx.x * 1024 + threadIdx.x * 4;
    int d[4];
    int s = 0;
#pragma unroll
    for (int i = 0; i < 4; ++i) {
        int idx = base + i;
        d[i] = (idx < N) ? deg[idx] : 0;
        s += d[i];
    }
    sh[threadIdx.x] = s;
    __syncthreads();
#pragma unroll
    for (int off = 1; off < 256; off <<= 1) {
        int y = (threadIdx.x >= (unsigned)off) ? sh[threadIdx.x - off] : 0;
        __syncthreads();
        sh[threadIdx.x] += y;
        __syncthreads();
    }
    int ex = partial[blockIdx.x] + sh[threadIdx.x] - s;
#pragma unroll
    for (int i = 0; i < 4; ++i) {
        int idx = base + i;
        if (idx < N) {
            offsets[idx] = ex;
            cur[idx] = ex;
            dinv[idx] = rsqrtf((float)(d[i] + 1));
            ex += d[i];
        }
    }
    if (blockIdx.x == 0 && threadIdx.x == 0) offsets[N] = E;
}

// ---------------- scatter: edge_src CSR fill ----------------

__global__ __launch_bounds__(256) void scatter_kernel(const int* __restrict__ rowv,
                                                      const int* __restrict__ colv,
                                                      int* __restrict__ cur,
                                                      int* __restrict__ edge_src, int E) {
    int i = (blockIdx.x * 256 + threadIdx.x) * 4;
    if (i + 4 <= E) {
        int4 c4 = *(const int4*)&colv[i];
        int4 r4 = *(const int4*)&rowv[i];
        int p0 = atomicAdd(&cur[c4.x], 1);
        int p1 = atomicAdd(&cur[c4.y], 1);
        int p2 = atomicAdd(&cur[c4.z], 1);
        int p3 = atomicAdd(&cur[c4.w], 1);
        edge_src[p0] = r4.x;
        edge_src[p1] = r4.y;
        edge_src[p2] = r4.z;
        edge_src[p3] = r4.w;
    } else {
        for (; i < E; ++i) {
            int p = atomicAdd(&cur[colv[i]], 1);
            edge_src[p] = rowv[i];
        }
    }
}

// ---------------- GEMM + dinv scale, fp16 out ----------------

template <int K, int NOUT>
__global__ __launch_bounds__(16 * (NOUT / 4)) void gemm_scale(const float* __restrict__ in_,
                                                              const float* __restrict__ W,
                                                              const float* __restrict__ dinv,
                                                              __half* __restrict__ out, int N) {
    constexpr int TPB = 16 * (NOUT / 4);
    constexpr int XPITCH = K + 4;
    __shared__ float xs[64 * XPITCH];
    __shared__ float ws[K * NOUT];

    const int tid = threadIdx.x;
    const int nodeBase = blockIdx.x * 64;

    for (int i = tid; i < K * NOUT / 4; i += TPB)
        *(float4*)&ws[i * 4] = *(const float4*)&W[i * 4];
    for (int i = tid; i < 64 * K / 4; i += TPB) {
        int row = i / (K / 4), c = i % (K / 4);
        int src = nodeBase + row; if (src >= N) src = N - 1;
        *(float4*)&xs[row * XPITCH + c * 4] = *(const float4*)&in_[(size_t)src * K + c * 4];
    }
    __syncthreads();

    const int jg = tid % (NOUT / 4);
    const int ng = tid / (NOUT / 4);

    float acc[4][4];
#pragma unroll
    for (int i = 0; i < 4; ++i)
#pragma unroll
        for (int j = 0; j < 4; ++j) acc[i][j] = 0.f;

    for (int kc = 0; kc < K / 4; ++kc) {
        float4 xv[4], wv[4];
#pragma unroll
        for (int ni = 0; ni < 4; ++ni)
            xv[ni] = *(const float4*)&xs[(ng * 4 + ni) * XPITCH + kc * 4];
#pragma unroll
        for (int t = 0; t < 4; ++t)
            wv[t] = *(const float4*)&ws[(kc * 4 + t) * NOUT + jg * 4];
#pragma unroll
        for (int ni = 0; ni < 4; ++ni) {
            acc[ni][0] = fmaf(xv[ni].x, wv[0].x, acc[ni][0]);
            acc[ni][1] = fmaf(xv[ni].x, wv[0].y, acc[ni][1]);
            acc[ni][2] = fmaf(xv[ni].x, wv[0].z, acc[ni][2]);
            acc[ni][3] = fmaf(xv[ni].x, wv[0].w, acc[ni][3]);
            acc[ni][0] = fmaf(xv[ni].y, wv[1].x, acc[ni][0]);
            acc[ni][1] = fmaf(xv[ni].y, wv[1].y, acc[ni][1]);
            acc[ni][2] = fmaf(xv[ni].y, wv[1].z, acc[ni][2]);
            acc[ni][3] = fmaf(xv[ni].y, wv[1].w, acc[ni][3]);
            acc[ni][0] = fmaf(xv[ni].z, wv[2].x, acc[ni][0]);
            acc[ni][1] = fmaf(xv[ni].z, wv[2].y, acc[ni][1]);
            acc[ni][2] = fmaf(xv[ni].z, wv[2].z, acc[ni][2]);
            acc[ni][3] = fmaf(xv[ni].z, wv[2].w, acc[ni][3]);
            acc[ni][0] = fmaf(xv[ni].w, wv[3].x, acc[ni][0]);
            acc[ni][1] = fmaf(xv[ni].w, wv[3].y, acc[ni][1]);
            acc[ni][2] = fmaf(xv[ni].w, wv[3].z, acc[ni][2]);
            acc[ni][3] = fmaf(xv[ni].w, wv[3].w, acc[ni][3]);
        }
    }

#pragma unroll
    for (int ni = 0; ni < 4; ++ni) {
        int node = nodeBase + ng * 4 + ni;
        if (node < N) {
            float dn = dinv[node];
            __half2* op = (__half2*)(out + (size_t)node * NOUT + jg * 4);
            op[0] = __floats2half2_rn(acc[ni][0] * dn, acc[ni][1] * dn);
            op[1] = __floats2half2_rn(acc[ni][2] * dn, acc[ni][3] * dn);
        }
    }
}

// ---------------- Pull aggregation: packed half2 gathers, fp32 accumulate ----------------

template <int F, bool RELU>
__global__ __launch_bounds__(256) void agg_pull(const __half* __restrict__ h,
                                                const float* __restrict__ dinv,
                                                const float* __restrict__ bias,
                                                const int* __restrict__ edge_src,
                                                const int* __restrict__ offsets,
                                                float* __restrict__ out, int N) {
    constexpr int LPN = F / 2;        // lanes per node
    constexpr int GPW = 64 / LPN;     // nodes per wave
    int lane = threadIdx.x & 63;
    int wave = (blockIdx.x * 256 + (int)threadIdx.x) >> 6;
    int g = lane / LPN;
    int fl = lane % LPN;              // feature-pair index
    int node = wave * GPW + g;
    if (node >= N) return;
    float dn = dinv[node];
    int beg = offsets[node], end = offsets[node + 1];
    const __half2* __restrict__ hp = (const __half2*)h;

    float2 sv = __half22float2(hp[(size_t)node * LPN + fl]);  // self-loop
    float a0x = sv.x, a0y = sv.y;
    float a1x = 0.f, a1y = 0.f, a2x = 0.f, a2y = 0.f, a3x = 0.f, a3y = 0.f;

    int j = beg;
    for (; j + 8 <= end; j += 8) {
        int s0 = edge_src[j],     s1 = edge_src[j + 1], s2 = edge_src[j + 2], s3 = edge_src[j + 3];
        int s4 = edge_src[j + 4], s5 = edge_src[j + 5], s6 = edge_src[j + 6], s7 = edge_src[j + 7];
        __half2 v0 = hp[(size_t)s0 * LPN + fl];
        __half2 v1 = hp[(size_t)s1 * LPN + fl];
        __half2 v2 = hp[(size_t)s2 * LPN + fl];
        __half2 v3 = hp[(size_t)s3 * LPN + fl];
        __half2 v4 = hp[(size_t)s4 * LPN + fl];
        __half2 v5 = hp[(size_t)s5 * LPN + fl];
        __half2 v6 = hp[(size_t)s6 * LPN + fl];
        __half2 v7 = hp[(size_t)s7 * LPN + fl];
        float2 f0 = __half22float2(v0), f1 = __half22float2(v1);
        float2 f2 = __half22float2(v2), f3 = __half22float2(v3);
        float2 f4 = __half22float2(v4), f5 = __half22float2(v5);
        float2 f6 = __half22float2(v6), f7 = __half22float2(v7);
        a0x += f0.x; a0y += f0.y; a1x += f1.x; a1y += f1.y;
        a2x += f2.x; a2y += f2.y; a3x += f3.x; a3y += f3.y;
        a0x += f4.x; a0y += f4.y; a1x += f5.x; a1y += f5.y;
        a2x += f6.x; a2y += f6.y; a3x += f7.x; a3y += f7.y;
    }
    for (; j + 2 <= end; j += 2) {
        int s0 = edge_src[j], s1 = edge_src[j + 1];
        float2 f0 = __half22float2(hp[(size_t)s0 * LPN + fl]);
        float2 f1 = __half22float2(hp[(size_t)s1 * LPN + fl]);
        a0x += f0.x; a0y += f0.y; a1x += f1.x; a1y += f1.y;
    }
    if (j < end) {
        float2 f0 = __half22float2(hp[(size_t)edge_src[j] * LPN + fl]);
        a0x += f0.x; a0y += f0.y;
    }

    float2 bv = *(const float2*)&bias[fl * 2];
    float rx = ((a0x + a1x) + (a2x + a3x)) * dn + bv.x;
    float ry = ((a0y + a1y) + (a2y + a3y)) * dn + bv.y;
    if (RELU) { rx = fmaxf(rx, 0.f); ry = fmaxf(ry, 0.f); }
    *(float2*)&out[(size_t)node * F + fl * 2] = make_float2(rx, ry);
}

// ---------------- Decode stage 1: uv[n] = [z@W1_top | z@W1_bot] (fp16 out) ----------------

__global__ __launch_bounds__(256) void gemm_uv(const float* __restrict__ z,   // [N,32]
                                               const float* __restrict__ W1,  // [64,64]
                                               __half* __restrict__ uv, int N) {
    constexpr int ZPITCH = 36;
    __shared__ float zs[64 * ZPITCH];
    __shared__ float ws[64 * 64];
    const int tid = threadIdx.x;
    const int nodeBase = blockIdx.x * 64;

    for (int i = tid; i < 64 * 64 / 4; i += 256)
        *(float4*)&ws[i * 4] = *(const float4*)&W1[i * 4];
    for (int i = tid; i < 64 * 8; i += 256) {
        int row = i / 8, c = i % 8;
        int src = nodeBase + row; if (src >= N) src = N - 1;
        *(float4*)&zs[row * ZPITCH + c * 4] = *(const float4*)&z[(size_t)src * 32 + c * 4];
    }
    __syncthreads();

    const int jg = tid % 16;
    const int ng = tid / 16;

    float au[4][4], av[4][4];
#pragma unroll
    for (int i = 0; i < 4; ++i)
#pragma unroll
        for (int j = 0; j < 4; ++j) { au[i][j] = 0.f; av[i][j] = 0.f; }

    for (int kc = 0; kc < 8; ++kc) {            // K = 32
        float4 xv[4], wu[4], wv2[4];
#pragma unroll
        for (int ni = 0; ni < 4; ++ni)
            xv[ni] = *(const float4*)&zs[(ng * 4 + ni) * ZPITCH + kc * 4];
#pragma unroll
        for (int t = 0; t < 4; ++t) {
            wu[t]  = *(const float4*)&ws[(kc * 4 + t) * 64 + jg * 4];
            wv2[t] = *(const float4*)&ws[(32 + kc * 4 + t) * 64 + jg * 4];
        }
#pragma unroll
        for (int ni = 0; ni < 4; ++ni) {
            float xk[4] = {xv[ni].x, xv[ni].y, xv[ni].z, xv[ni].w};
#pragma unroll
            for (int t = 0; t < 4; ++t) {
                au[ni][0] = fmaf(xk[t], wu[t].x, au[ni][0]);
                au[ni][1] = fmaf(xk[t], wu[t].y, au[ni][1]);
                au[ni][2] = fmaf(xk[t], wu[t].z, au[ni][2]);
                au[ni][3] = fmaf(xk[t], wu[t].w, au[ni][3]);
                av[ni][0] = fmaf(xk[t], wv2[t].x, av[ni][0]);
                av[ni][1] = fmaf(xk[t], wv2[t].y, av[ni][1]);
                av[ni][2] = fmaf(xk[t], wv2[t].z, av[ni][2]);
                av[ni][3] = fmaf(xk[t], wv2[t].w, av[ni][3]);
            }
        }
    }

#pragma unroll
    for (int ni = 0; ni < 4; ++ni) {
        int node = nodeBase + ng * 4 + ni;
        if (node < N) {
            __half2* pu = (__half2*)(uv + (size_t)node * 128 + jg * 4);
            pu[0] = __floats2half2_rn(au[ni][0], au[ni][1]);
            pu[1] = __floats2half2_rn(au[ni][2], au[ni][3]);
            __half2* pv = (__half2*)(uv + (size_t)node * 128 + 64 + jg * 4);
            pv[0] = __floats2half2_rn(av[ni][0], av[ni][1]);
            pv[1] = __floats2half2_rn(av[ni][2], av[ni][3]);
        }
    }
}

// ---------------- Decode stage 2: link_pred[e] = relu(u[a]+v[b]+b1)·w2 + b2 ----------------

__global__ __launch_bounds__(256) void decode_edge(const __half* __restrict__ uv,
                                                   const int* __restrict__ eli, int EL,
                                                   const float* __restrict__ lpb1,
                                                   const float* __restrict__ lpW2,
                                                   const float* __restrict__ lpb2,
                                                   float* __restrict__ out) {
    const int sub = threadIdx.x & 15;
    float4 b1r = *(const float4*)&lpb1[sub * 4];
    float4 w2r = *(const float4*)&lpW2[sub * 4];
    const float b2v = lpb2[0];
    int e = blockIdx.x * 16 + (threadIdx.x >> 4);
    if (e >= EL) return;
    int a = eli[e], b = eli[EL + e];
    const __half2* pa = (const __half2*)(uv + (size_t)a * 128 + sub * 4);
    const __half2* pb = (const __half2*)(uv + (size_t)b * 128 + 64 + sub * 4);
    float2 a01 = __half22float2(pa[0]), a23 = __half22float2(pa[1]);
    float2 b01 = __half22float2(pb[0]), b23 = __half22float2(pb[1]);
    float p = fmaxf(a01.x + b01.x + b1r.x, 0.f) * w2r.x;
    p = fmaf(fmaxf(a01.y + b01.y + b1r.y, 0.f), w2r.y, p);
    p = fmaf(fmaxf(a23.x + b23.x + b1r.z, 0.f), w2r.z, p);
    p = fmaf(fmaxf(a23.y + b23.y + b1r.w, 0.f), w2r.w, p);
    p += __shfl_down(p, 8, 16);
    p += __shfl_down(p, 4, 16);
    p += __shfl_down(p, 2, 16);
    p += __shfl_down(p, 1, 16);
    if (sub == 0) out[e] = p + b2v;
}

// ---------------- launch ----------------

extern "C" void kernel_launch(void* const* d_in, const int* in_sizes, int n_in,
                              void* d_out, int out_size, void* d_ws, size_t ws_size,
                              hipStream_t stream) {
    const float* x    = (const float*)d_in[0];
    const int* ei     = (const int*)d_in[1];
    const int* eli    = (const int*)d_in[2];
    const float* W1   = (const float*)d_in[3];
    const float* b1   = (const float*)d_in[4];
    const float* W2   = (const float*)d_in[5];
    const float* b2   = (const float*)d_in[6];
    const float* W3   = (const float*)d_in[7];
    const float* b3   = (const float*)d_in[8];
    const float* lpW1 = (const float*)d_in[9];
    const float* lpb1 = (const float*)d_in[10];
    const float* lpW2 = (const float*)d_in[11];
    const float* lpb2 = (const float*)d_in[12];

    const int N  = in_sizes[0] / 128;   // 100000
    const int E  = in_sizes[1] / 2;     // 3200000
    const int EL = in_sizes[2] / 2;     // 1000000

    char* p = (char*)d_ws;
    auto alloc = [&](size_t bytes) { void* r = (void*)p; p += (bytes + 255) & ~(size_t)255; return r; };
    float* dinv     = (float*)alloc((size_t)N * 4);
    int*   offsets  = (int*)alloc((size_t)(N + 1) * 4);
    int*   deg      = (int*)alloc((size_t)N * 4);
    int*   cur      = (int*)alloc((size_t)N * 4);
    int*   partial  = (int*)alloc(128 * 4);
    int*   edge_src = (int*)alloc((size_t)E * 4);
    __half* bufG    = (__half*)alloc((size_t)N * 64 * 2);   // fp16 messages h'
    float* bufZ     = (float*)alloc((size_t)N * 64 * 4);    // fp32 z1/z2
    __half* uvbuf   = (__half*)alloc((size_t)N * 128 * 2);  // fp16 uv

    const int* rowv = ei;        // edge_index[0] = source
    const int* colv = ei + E;    // edge_index[1] = target

    const int NB = (N + 1023) / 1024;          // 98 scan blocks
    const int eblocks = (E + 1023) / 1024;     // 3125: 4 edges/thread, 256 thr/block

    hipMemsetAsync(deg, 0, (size_t)N * 4, stream);
    deg_hist<<<eblocks, 256, 0, stream>>>(colv, deg, E);
    scan1<<<NB, 256, 0, stream>>>(deg, partial, N);
    scan2<<<1, 128, 0, stream>>>(partial, NB);
    scan3<<<NB, 256, 0, stream>>>(deg, partial, offsets, cur, dinv, N, E);
    scatter_kernel<<<eblocks, 256, 0, stream>>>(rowv, colv, cur, edge_src, E);

    float* zout = (float*)d_out + EL;   // z lives in the output tail (float32)

    int gblocks = (N + 63) / 64;  // 1563

    // agg_pull packed: GPW = 128/F nodes per wave; 4 waves per block.
    int aggblocks64 = (N + 7) / 8;     // F=64: 2 nodes/wave * 4 waves
    int aggblocks32 = (N + 15) / 16;   // F=32: 4 nodes/wave * 4 waves

    // layer 1: x[N,128] -> bufG h' (fp16) -> bufZ (fp32, relu)
    gemm_scale<128, 64><<<gblocks, 256, 0, stream>>>(x, W1, dinv, bufG, N);
    agg_pull<64, true><<<aggblocks64, 256, 0, stream>>>(bufG, dinv, b1, edge_src, offsets, bufZ, N);
    // layer 2
    gemm_scale<64, 64><<<gblocks, 256, 0, stream>>>(bufZ, W2, dinv, bufG, N);
    agg_pull<64, true><<<aggblocks64, 256, 0, stream>>>(bufG, dinv, b2, edge_src, offsets, bufZ, N);
    // layer 3: 32-wide, write z directly into d_out tail
    gemm_scale<64, 32><<<gblocks, 128, 0, stream>>>(bufZ, W3, dinv, bufG, N);
    agg_pull<32, false><<<aggblocks32, 256, 0, stream>>>(bufG, dinv, b3, edge_src, offsets, zout, N);
    // decode: per-node uv precompute (fp16), then per-edge gather+epilogue
    gemm_uv<<<gblocks, 256, 0, stream>>>(zout, lpW1, uvbuf, N);
    decode_edge<<<(EL + 15) / 16, 256, 0, stream>>>(uvbuf, eli, EL, lpb1, lpW2, lpb2, (float*)d_out);
}

// Round 2
// 544.923 us; speedup vs baseline: 1.6264x; 1.6264x over previous
//
#include <hip/hip_runtime.h>
#include <hip/hip_bf16.h>
#include <hip/hip_fp16.h>

// MusicGNN — 3-layer GCN encoder + MLP link predictor.
// N=100000, F_IN=128, HID=64, OUT=32, E=3.2M edges, EL=1M label edges.
// Inputs: float32 (x, weights, biases), int32 (edge indices).
// Output float32: [link_pred (1M) | z (100000*32)] concatenated flat.
//
// R13: revert R12 (direct per-node scatter was 300us: 15x write
// amplification + dependent returning-atomic->scattered-4B-store chains).
// Back to R11's two-level bucket sort, minus its redundancy: bhist now
// persists per-chunk histograms chist[chunk][bucket]; a column scan over
// chunks gives every chunk its deterministic base offset in every bucket.
// binA then skips its phase-1 histogram recompute (one less pass over
// colv, half the LDS atomics) and does ZERO global atomics (previously
// 611k contended returning atomicAdds on bcur).

#define BINA_CHUNK 4096

// ---------------- per-chunk bucket histogram ----------------

__global__ __launch_bounds__(512) void bhist_kernel(const int* __restrict__ colv,
                                                    int* __restrict__ chist,
                                                    int E, int nbuk) {
    __shared__ int hist[800];
    int base = blockIdx.x * BINA_CHUNK;
    int end = min(base + BINA_CHUNK, E);
    for (int i = threadIdx.x; i < nbuk; i += 512) hist[i] = 0;
    __syncthreads();
    int e = base + threadIdx.x * 4;
    for (; e + 4 <= end; e += 2048) {
        int4 c4 = *(const int4*)&colv[e];
        atomicAdd(&hist[c4.x >> 7], 1);
        atomicAdd(&hist[c4.y >> 7], 1);
        atomicAdd(&hist[c4.z >> 7], 1);
        atomicAdd(&hist[c4.w >> 7], 1);
    }
    for (; e < end; ++e) atomicAdd(&hist[colv[e] >> 7], 1);
    __syncthreads();
    for (int b = threadIdx.x; b < nbuk; b += 512)
        chist[(size_t)blockIdx.x * nbuk + b] = hist[b];
}

// ---------------- column scan: chist[c][b] -> exclusive prefix over c ----------------
// one block per bucket; also emits column total -> bcount[b]. nchunk <= 1024.

__global__ __launch_bounds__(256) void colscan_kernel(int* __restrict__ chist,
                                                      int* __restrict__ bcount,
                                                      int nchunk, int nbuk) {
    __shared__ int sh[256];
    const int b = blockIdx.x;
    const int c0 = threadIdx.x * 4;
    int v[4]; int s = 0;
#pragma unroll
    for (int i = 0; i < 4; ++i) {
        int c = c0 + i;
        v[i] = (c < nchunk) ? chist[(size_t)c * nbuk + b] : 0;
        s += v[i];
    }
    sh[threadIdx.x] = s;
    __syncthreads();
#pragma unroll
    for (int off = 1; off < 256; off <<= 1) {
        int y = (threadIdx.x >= (unsigned)off) ? sh[threadIdx.x - off] : 0;
        __syncthreads();
        sh[threadIdx.x] += y;
        __syncthreads();
    }
    int ex = sh[threadIdx.x] - s;
#pragma unroll
    for (int i = 0; i < 4; ++i) {
        int c = c0 + i;
        if (c < nchunk) { chist[(size_t)c * nbuk + b] = ex; ex += v[i]; }
    }
    if (threadIdx.x == 255) bcount[b] = sh[255];
}

// ---------------- bucket scan ----------------

__global__ __launch_bounds__(256) void bscan_kernel(const int* __restrict__ bcount,
                                                    int* __restrict__ bbase,
                                                    int nbuk, int* __restrict__ offsets, int N) {
    __shared__ int sh[256];
    int base = threadIdx.x * 4;
    int v[4]; int tsum = 0;
#pragma unroll
    for (int i = 0; i < 4; ++i) { int idx = base + i; v[i] = (idx < nbuk) ? bcount[idx] : 0; tsum += v[i]; }
    sh[threadIdx.x] = tsum;
    __syncthreads();
#pragma unroll
    for (int off = 1; off < 256; off <<= 1) {
        int y = (threadIdx.x >= (unsigned)off) ? sh[threadIdx.x - off] : 0;
        __syncthreads();
        sh[threadIdx.x] += y;
        __syncthreads();
    }
    int ex = sh[threadIdx.x] - tsum;
#pragma unroll
    for (int i = 0; i < 4; ++i) {
        int idx = base + i;
        if (idx < nbuk) { bbase[idx] = ex; ex += v[i]; }
        else if (idx == nbuk) { bbase[idx] = ex; offsets[N] = ex; }  // = E
    }
}

// ---------------- Phase A: scatter into buckets (deterministic chunk bases) ----------------

__global__ __launch_bounds__(512) void binA_kernel(const int* __restrict__ rowv,
                                                   const int* __restrict__ colv,
                                                   const int* __restrict__ chist,
                                                   const int* __restrict__ bbase,
                                                   int* __restrict__ pairs,
                                                   int E, int nbuk) {
    __shared__ int pos[800];
    int base = blockIdx.x * BINA_CHUNK;
    int end = min(base + BINA_CHUNK, E);
    for (int b = threadIdx.x; b < nbuk; b += 512)
        pos[b] = bbase[b] + chist[(size_t)blockIdx.x * nbuk + b];
    __syncthreads();
    int e = base + threadIdx.x * 4;
    for (; e + 4 <= end; e += 2048) {
        int4 c4 = *(const int4*)&colv[e];
        int4 r4 = *(const int4*)&rowv[e];
        int g0 = atomicAdd(&pos[c4.x >> 7], 1); pairs[g0] = (r4.x << 7) | (c4.x & 127);
        int g1 = atomicAdd(&pos[c4.y >> 7], 1); pairs[g1] = (r4.y << 7) | (c4.y & 127);
        int g2 = atomicAdd(&pos[c4.z >> 7], 1); pairs[g2] = (r4.z << 7) | (c4.z & 127);
        int g3 = atomicAdd(&pos[c4.w >> 7], 1); pairs[g3] = (r4.w << 7) | (c4.w & 127);
    }
    for (; e < end; ++e) {
        int c = colv[e];
        int g = atomicAdd(&pos[c >> 7], 1);
        pairs[g] = (rowv[e] << 7) | (c & 127);
    }
}

// ---------------- Phase B: per bucket — node hist, scan, offsets+dinv, scatter ----------------

__global__ __launch_bounds__(512) void binB_kernel(const int* __restrict__ pairs,
                                                   const int* __restrict__ bbase,
                                                   int* __restrict__ offsets,
                                                   float* __restrict__ dinv,
                                                   int* __restrict__ edge_src, int N) {
    __shared__ int lcnt[128];
    __shared__ int sc[128];
    __shared__ int lcur[128];
    int nodeBeg = blockIdx.x << 7;
    int segBeg = bbase[blockIdx.x];
    int segEnd = bbase[blockIdx.x + 1];
    if (threadIdx.x < 128) lcnt[threadIdx.x] = 0;
    __syncthreads();
    for (int e = segBeg + threadIdx.x; e < segEnd; e += 512)
        atomicAdd(&lcnt[pairs[e] & 127], 1);
    __syncthreads();
    int v = (threadIdx.x < 128) ? lcnt[threadIdx.x] : 0;
    if (threadIdx.x < 128) sc[threadIdx.x] = v;
    __syncthreads();
    for (int off = 1; off < 128; off <<= 1) {
        int y = 0;
        if (threadIdx.x < 128 && threadIdx.x >= (unsigned)off) y = sc[threadIdx.x - off];
        __syncthreads();
        if (threadIdx.x < 128) sc[threadIdx.x] += y;
        __syncthreads();
    }
    if (threadIdx.x < 128) {
        int ex = sc[threadIdx.x] - v;
        lcur[threadIdx.x] = ex;
        int node = nodeBeg + threadIdx.x;
        if (node < N) {
            offsets[node] = segBeg + ex;
            dinv[node] = rsqrtf((float)(v + 1));
        }
    }
    __syncthreads();
    for (int e = segBeg + threadIdx.x; e < segEnd; e += 512) {
        int p = pairs[e];
        int rel = atomicAdd(&lcur[p & 127], 1);
        edge_src[segBeg + rel] = p >> 7;
    }
}

// ---------------- GEMM + dinv scale, fp16 out ----------------

template <int K, int NOUT>
__global__ __launch_bounds__(16 * (NOUT / 4)) void gemm_scale(const float* __restrict__ in_,
                                                              const float* __restrict__ W,
                                                              const float* __restrict__ dinv,
                                                              __half* __restrict__ out, int N) {
    constexpr int TPB = 16 * (NOUT / 4);
    constexpr int XPITCH = K + 4;
    __shared__ float xs[64 * XPITCH];
    __shared__ float ws[K * NOUT];

    const int tid = threadIdx.x;
    const int nodeBase = blockIdx.x * 64;

    for (int i = tid; i < K * NOUT / 4; i += TPB)
        *(float4*)&ws[i * 4] = *(const float4*)&W[i * 4];
    for (int i = tid; i < 64 * K / 4; i += TPB) {
        int row = i / (K / 4), c = i % (K / 4);
        int src = nodeBase + row; if (src >= N) src = N - 1;
        *(float4*)&xs[row * XPITCH + c * 4] = *(const float4*)&in_[(size_t)src * K + c * 4];
    }
    __syncthreads();

    const int jg = tid % (NOUT / 4);
    const int ng = tid / (NOUT / 4);

    float acc[4][4];
#pragma unroll
    for (int i = 0; i < 4; ++i)
#pragma unroll
        for (int j = 0; j < 4; ++j) acc[i][j] = 0.f;

    for (int kc = 0; kc < K / 4; ++kc) {
        float4 xv[4], wv[4];
#pragma unroll
        for (int ni = 0; ni < 4; ++ni)
            xv[ni] = *(const float4*)&xs[(ng * 4 + ni) * XPITCH + kc * 4];
#pragma unroll
        for (int t = 0; t < 4; ++t)
            wv[t] = *(const float4*)&ws[(kc * 4 + t) * NOUT + jg * 4];
#pragma unroll
        for (int ni = 0; ni < 4; ++ni) {
            acc[ni][0] = fmaf(xv[ni].x, wv[0].x, acc[ni][0]);
            acc[ni][1] = fmaf(xv[ni].x, wv[0].y, acc[ni][1]);
            acc[ni][2] = fmaf(xv[ni].x, wv[0].z, acc[ni][2]);
            acc[ni][3] = fmaf(xv[ni].x, wv[0].w, acc[ni][3]);
            acc[ni][0] = fmaf(xv[ni].y, wv[1].x, acc[ni][0]);
            acc[ni][1] = fmaf(xv[ni].y, wv[1].y, acc[ni][1]);
            acc[ni][2] = fmaf(xv[ni].y, wv[1].z, acc[ni][2]);
            acc[ni][3] = fmaf(xv[ni].y, wv[1].w, acc[ni][3]);
            acc[ni][0] = fmaf(xv[ni].z, wv[2].x, acc[ni][0]);
            acc[ni][1] = fmaf(xv[ni].z, wv[2].y, acc[ni][1]);
            acc[ni][2] = fmaf(xv[ni].z, wv[2].z, acc[ni][2]);
            acc[ni][3] = fmaf(xv[ni].z, wv[2].w, acc[ni][3]);
            acc[ni][0] = fmaf(xv[ni].w, wv[3].x, acc[ni][0]);
            acc[ni][1] = fmaf(xv[ni].w, wv[3].y, acc[ni][1]);
            acc[ni][2] = fmaf(xv[ni].w, wv[3].z, acc[ni][2]);
            acc[ni][3] = fmaf(xv[ni].w, wv[3].w, acc[ni][3]);
        }
    }

#pragma unroll
    for (int ni = 0; ni < 4; ++ni) {
        int node = nodeBase + ng * 4 + ni;
        if (node < N) {
            float dn = dinv[node];
            __half2* op = (__half2*)(out + (size_t)node * NOUT + jg * 4);
            op[0] = __floats2half2_rn(acc[ni][0] * dn, acc[ni][1] * dn);
            op[1] = __floats2half2_rn(acc[ni][2] * dn, acc[ni][3] * dn);
        }
    }
}

// ---------------- Pull aggregation: packed half2 gathers, fp32 accumulate ----------------

template <int F, bool RELU>
__global__ __launch_bounds__(256) void agg_pull(const __half* __restrict__ h,
                                                const float* __restrict__ dinv,
                                                const float* __restrict__ bias,
                                                const int* __restrict__ edge_src,
                                                const int* __restrict__ offsets,
                                                float* __restrict__ out, int N) {
    constexpr int LPN = F / 2;        // lanes per node
    constexpr int GPW = 64 / LPN;     // nodes per wave
    int lane = threadIdx.x & 63;
    int wave = (blockIdx.x * 256 + (int)threadIdx.x) >> 6;
    int g = lane / LPN;
    int fl = lane % LPN;              // feature-pair index
    int node = wave * GPW + g;
    if (node >= N) return;
    float dn = dinv[node];
    int beg = offsets[node], end = offsets[node + 1];
    const __half2* __restrict__ hp = (const __half2*)h;

    float2 sv = __half22float2(hp[(size_t)node * LPN + fl]);  // self-loop
    float a0x = sv.x, a0y = sv.y;
    float a1x = 0.f, a1y = 0.f, a2x = 0.f, a2y = 0.f, a3x = 0.f, a3y = 0.f;

    int j = beg;
    for (; j + 8 <= end; j += 8) {
        int s0 = edge_src[j],     s1 = edge_src[j + 1], s2 = edge_src[j + 2], s3 = edge_src[j + 3];
        int s4 = edge_src[j + 4], s5 = edge_src[j + 5], s6 = edge_src[j + 6], s7 = edge_src[j + 7];
        __half2 v0 = hp[(size_t)s0 * LPN + fl];
        __half2 v1 = hp[(size_t)s1 * LPN + fl];
        __half2 v2 = hp[(size_t)s2 * LPN + fl];
        __half2 v3 = hp[(size_t)s3 * LPN + fl];
        __half2 v4 = hp[(size_t)s4 * LPN + fl];
        __half2 v5 = hp[(size_t)s5 * LPN + fl];
        __half2 v6 = hp[(size_t)s6 * LPN + fl];
        __half2 v7 = hp[(size_t)s7 * LPN + fl];
        float2 f0 = __half22float2(v0), f1 = __half22float2(v1);
        float2 f2 = __half22float2(v2), f3 = __half22float2(v3);
        float2 f4 = __half22float2(v4), f5 = __half22float2(v5);
        float2 f6 = __half22float2(v6), f7 = __half22float2(v7);
        a0x += f0.x; a0y += f0.y; a1x += f1.x; a1y += f1.y;
        a2x += f2.x; a2y += f2.y; a3x += f3.x; a3y += f3.y;
        a0x += f4.x; a0y += f4.y; a1x += f5.x; a1y += f5.y;
        a2x += f6.x; a2y += f6.y; a3x += f7.x; a3y += f7.y;
    }
    for (; j + 2 <= end; j += 2) {
        int s0 = edge_src[j], s1 = edge_src[j + 1];
        float2 f0 = __half22float2(hp[(size_t)s0 * LPN + fl]);
        float2 f1 = __half22float2(hp[(size_t)s1 * LPN + fl]);
        a0x += f0.x; a0y += f0.y; a1x += f1.x; a1y += f1.y;
    }
    if (j < end) {
        float2 f0 = __half22float2(hp[(size_t)edge_src[j] * LPN + fl]);
        a0x += f0.x; a0y += f0.y;
    }

    float2 bv = *(const float2*)&bias[fl * 2];
    float rx = ((a0x + a1x) + (a2x + a3x)) * dn + bv.x;
    float ry = ((a0y + a1y) + (a2y + a3y)) * dn + bv.y;
    if (RELU) { rx = fmaxf(rx, 0.f); ry = fmaxf(ry, 0.f); }
    *(float2*)&out[(size_t)node * F + fl * 2] = make_float2(rx, ry);
}

// ---------------- Decode stage 1: uv[n] = [z@W1_top | z@W1_bot] (fp16 out) ----------------

__global__ __launch_bounds__(256) void gemm_uv(const float* __restrict__ z,   // [N,32]
                                               const float* __restrict__ W1,  // [64,64]
                                               __half* __restrict__ uv, int N) {
    constexpr int ZPITCH = 36;
    __shared__ float zs[64 * ZPITCH];
    __shared__ float ws[64 * 64];
    const int tid = threadIdx.x;
    const int nodeBase = blockIdx.x * 64;

    for (int i = tid; i < 64 * 64 / 4; i += 256)
        *(float4*)&ws[i * 4] = *(const float4*)&W1[i * 4];
    for (int i = tid; i < 64 * 8; i += 256) {
        int row = i / 8, c = i % 8;
        int src = nodeBase + row; if (src >= N) src = N - 1;
        *(float4*)&zs[row * ZPITCH + c * 4] = *(const float4*)&z[(size_t)src * 32 + c * 4];
    }
    __syncthreads();

    const int jg = tid % 16;
    const int ng = tid / 16;

    float au[4][4], av[4][4];
#pragma unroll
    for (int i = 0; i < 4; ++i)
#pragma unroll
        for (int j = 0; j < 4; ++j) { au[i][j] = 0.f; av[i][j] = 0.f; }

    for (int kc = 0; kc < 8; ++kc) {            // K = 32
        float4 xv[4], wu[4], wv2[4];
#pragma unroll
        for (int ni = 0; ni < 4; ++ni)
            xv[ni] = *(const float4*)&zs[(ng * 4 + ni) * ZPITCH + kc * 4];
#pragma unroll
        for (int t = 0; t < 4; ++t) {
            wu[t]  = *(const float4*)&ws[(kc * 4 + t) * 64 + jg * 4];
            wv2[t] = *(const float4*)&ws[(32 + kc * 4 + t) * 64 + jg * 4];
        }
#pragma unroll
        for (int ni = 0; ni < 4; ++ni) {
            float xk[4] = {xv[ni].x, xv[ni].y, xv[ni].z, xv[ni].w};
#pragma unroll
            for (int t = 0; t < 4; ++t) {
                au[ni][0] = fmaf(xk[t], wu[t].x, au[ni][0]);
                au[ni][1] = fmaf(xk[t], wu[t].y, au[ni][1]);
                au[ni][2] = fmaf(xk[t], wu[t].z, au[ni][2]);
                au[ni][3] = fmaf(xk[t], wu[t].w, au[ni][3]);
                av[ni][0] = fmaf(xk[t], wv2[t].x, av[ni][0]);
                av[ni][1] = fmaf(xk[t], wv2[t].y, av[ni][1]);
                av[ni][2] = fmaf(xk[t], wv2[t].z, av[ni][2]);
                av[ni][3] = fmaf(xk[t], wv2[t].w, av[ni][3]);
            }
        }
    }

#pragma unroll
    for (int ni = 0; ni < 4; ++ni) {
        int node = nodeBase + ng * 4 + ni;
        if (node < N) {
            __half2* pu = (__half2*)(uv + (size_t)node * 128 + jg * 4);
            pu[0] = __floats2half2_rn(au[ni][0], au[ni][1]);
            pu[1] = __floats2half2_rn(au[ni][2], au[ni][3]);
            __half2* pv = (__half2*)(uv + (size_t)node * 128 + 64 + jg * 4);
            pv[0] = __floats2half2_rn(av[ni][0], av[ni][1]);
            pv[1] = __floats2half2_rn(av[ni][2], av[ni][3]);
        }
    }
}

// ---------------- Decode stage 2: link_pred[e] = relu(u[a]+v[b]+b1)·w2 + b2 ----------------

__global__ __launch_bounds__(256) void decode_edge(const __half* __restrict__ uv,
                                                   const int* __restrict__ eli, int EL,
                                                   const float* __restrict__ lpb1,
                                                   const float* __restrict__ lpW2,
                                                   const float* __restrict__ lpb2,
                                                   float* __restrict__ out) {
    const int sub = threadIdx.x & 15;
    float4 b1r = *(const float4*)&lpb1[sub * 4];
    float4 w2r = *(const float4*)&lpW2[sub * 4];
    const float b2v = lpb2[0];
    int e = blockIdx.x * 16 + (threadIdx.x >> 4);
    if (e >= EL) return;
    int a = eli[e], b = eli[EL + e];
    const __half2* pa = (const __half2*)(uv + (size_t)a * 128 + sub * 4);
    const __half2* pb = (const __half2*)(uv + (size_t)b * 128 + 64 + sub * 4);
    float2 a01 = __half22float2(pa[0]), a23 = __half22float2(pa[1]);
    float2 b01 = __half22float2(pb[0]), b23 = __half22float2(pb[1]);
    float p = fmaxf(a01.x + b01.x + b1r.x, 0.f) * w2r.x;
    p = fmaf(fmaxf(a01.y + b01.y + b1r.y, 0.f), w2r.y, p);
    p = fmaf(fmaxf(a23.x + b23.x + b1r.z, 0.f), w2r.z, p);
    p = fmaf(fmaxf(a23.y + b23.y + b1r.w, 0.f), w2r.w, p);
    p += __shfl_down(p, 8, 16);
    p += __shfl_down(p, 4, 16);
    p += __shfl_down(p, 2, 16);
    p += __shfl_down(p, 1, 16);
    if (sub == 0) out[e] = p + b2v;
}

// ---------------- launch ----------------

extern "C" void kernel_launch(void* const* d_in, const int* in_sizes, int n_in,
                              void* d_out, int out_size, void* d_ws, size_t ws_size,
                              hipStream_t stream) {
    const float* x    = (const float*)d_in[0];
    const int* ei     = (const int*)d_in[1];
    const int* eli    = (const int*)d_in[2];
    const float* W1   = (const float*)d_in[3];
    const float* b1   = (const float*)d_in[4];
    const float* W2   = (const float*)d_in[5];
    const float* b2   = (const float*)d_in[6];
    const float* W3   = (const float*)d_in[7];
    const float* b3   = (const float*)d_in[8];
    const float* lpW1 = (const float*)d_in[9];
    const float* lpb1 = (const float*)d_in[10];
    const float* lpW2 = (const float*)d_in[11];
    const float* lpb2 = (const float*)d_in[12];

    const int N  = in_sizes[0] / 128;   // 100000
    const int E  = in_sizes[1] / 2;     // 3200000
    const int EL = in_sizes[2] / 2;     // 1000000

    char* p = (char*)d_ws;
    auto alloc = [&](size_t bytes) { void* r = (void*)p; p += (bytes + 255) & ~(size_t)255; return r; };
    float* dinv     = (float*)alloc((size_t)N * 4);
    int*   offsets  = (int*)alloc((size_t)(N + 1) * 4);
    int*   bcount   = (int*)alloc(1024 * 4);
    int*   bbase    = (int*)alloc(1024 * 4);
    int*   edge_src = (int*)alloc((size_t)E * 4);
    __half* bufG    = (__half*)alloc((size_t)N * 64 * 2);   // fp16 messages h'
    float* bufZ     = (float*)alloc((size_t)N * 64 * 4);    // fp32 z1/z2
    __half* uvbuf   = (__half*)alloc((size_t)N * 128 * 2);  // fp16 uv
    int*   pairs    = (int*)uvbuf;  // alias: pairs (12.8MB) dead before gemm_uv writes uv
    int*   chist    = (int*)bufZ;   // alias: chist (2.5MB) dead before agg_pull writes bufZ

    const int* rowv = ei;        // edge_index[0] = source
    const int* colv = ei + E;    // edge_index[1] = target

    int nbuk = (N + 127) / 128;                      // 782
    int nchunk = (E + BINA_CHUNK - 1) / BINA_CHUNK;  // 782 (<=1024 required by colscan)

    bhist_kernel<<<nchunk, 512, 0, stream>>>(colv, chist, E, nbuk);
    colscan_kernel<<<nbuk, 256, 0, stream>>>(chist, bcount, nchunk, nbuk);
    bscan_kernel<<<1, 256, 0, stream>>>(bcount, bbase, nbuk, offsets, N);
    binA_kernel<<<nchunk, 512, 0, stream>>>(rowv, colv, chist, bbase, pairs, E, nbuk);
    binB_kernel<<<nbuk, 512, 0, stream>>>(pairs, bbase, offsets, dinv, edge_src, N);

    float* zout = (float*)d_out + EL;   // z lives in the output tail (float32)

    int gblocks = (N + 63) / 64;  // 1563

    // agg_pull packed: GPW = 128/F nodes per wave; 4 waves per block.
    int aggblocks64 = (N + 7) / 8;     // F=64: 2 nodes/wave * 4 waves
    int aggblocks32 = (N + 15) / 16;   // F=32: 4 nodes/wave * 4 waves

    // layer 1: x[N,128] -> bufG h' (fp16) -> bufZ (fp32, relu)
    gemm_scale<128, 64><<<gblocks, 256, 0, stream>>>(x, W1, dinv, bufG, N);
    agg_pull<64, true><<<aggblocks64, 256, 0, stream>>>(bufG, dinv, b1, edge_src, offsets, bufZ, N);
    // layer 2
    gemm_scale<64, 64><<<gblocks, 256, 0, stream>>>(bufZ, W2, dinv, bufG, N);
    agg_pull<64, true><<<aggblocks64, 256, 0, stream>>>(bufG, dinv, b2, edge_src, offsets, bufZ, N);
    // layer 3: 32-wide, write z directly into d_out tail
    gemm_scale<64, 32><<<gblocks, 128, 0, stream>>>(bufZ, W3, dinv, bufG, N);
    agg_pull<32, false><<<aggblocks32, 256, 0, stream>>>(bufG, dinv, b3, edge_src, offsets, zout, N);
    // decode: per-node uv precompute (fp16), then per-edge gather+epilogue
    gemm_uv<<<gblocks, 256, 0, stream>>>(zout, lpW1, uvbuf, N);
    decode_edge<<<(EL + 15) / 16, 256, 0, stream>>>(uvbuf, eli, EL, lpb1, lpW2, lpb2, (float*)d_out);
}